// Round 7
// baseline (4779.807 us; speedup 1.0000x reference)
//
#include <hip/hip_runtime.h>
#include <hip/hip_bf16.h>

// ---------------- sizes ----------------
#define T_STEPS 256
#define MDIM 1024
#define MROWS 512
#define NBLK 256
#define GRID NBLK
#define NTHR 512

// ws float offsets
#define OFF_WGB     0u                      // bf16 [1024][4096] interleaved gates (2M floats)
#define OFF_WATT    2097152u                // fp32 [1024][1024] W_attnh top, transposed
#define OFF_HPRET   3145728u                // fp32 [1024][512]  Hpre TRANSPOSED
#define OFF_XIOU    3670016u                // fp32 [256][3072]
#define OFF_XF      4456448u                // fp32 [256][1024]
#define OFF_G       4718592u                // bf16 [512][4096]  G = H @ Wg
#define OFF_HT      5767168u                // fp32 [1024][512]  H transposed
#define OFF_HCOL    6291456u                // fp32 [1024]
#define OFF_HCOLW   6292480u                // fp32 [4096]  Hcol @ Wg
#define OFF_SCORED  6297600u                // f64 [2][32][512] count-biased score copies, COPY-MAJOR (zeroed)
#define OFF_HLINE   6363136u                // u64 [256][8]: 4 pairs {f32 h, u32 epoch} + pad (zeroed)

// R19 score reduction: 32 sub-copies (4 per XCD), RMW depth 8.
//  R18 post-mortem isolated same-address RMW serialization as the hidden
//  serial term (~75ns/RMW x depth). R15's depth was 32 (~2.4us/step).
//  Copy c = x*4 + (y&3): written by the 8 blocks sharing (x, y&3) -> all
//  same XCD (R16 erratum: atomic lines must be single-XCD-owned).
//  Consumer polls its element across all 32 copies with fused count-bias
//  detection (detection == payload, no extra RTs -- R18's decoupled
//  counter scheme added 2 RTs + its own depth-32 counter chain).
//  Settled copy value = 8*BIAS32 + partial; de-bias per copy subtracts
//  SUBBIAS=8*BIAS32 (Sterbenz-exact, vv in [2^35, 2^36)).
#define BIAS32  4294967296.0                // 2^32
#define SUBBIAS (8.0 * 4294967296.0)        // 2^35
#define DONE_TH (8.0 * 4294967296.0 - 1073741824.0)   // 8*2^32 - 2^30

__device__ inline float fast_tanh(float v) {
    float x = fminf(fmaxf(v, -15.f), 15.f);
    float z = __expf(2.f * x);
    return (z - 1.f) / (z + 1.f);
}
__device__ inline float sigm(float v) { return 1.f / (1.f + __expf(-v)); }

__device__ inline float wave_red(float v) {
#pragma unroll
    for (int s = 32; s > 0; s >>= 1) v += __shfl_down(v, s, 64);
    return v;
}

__device__ __host__ inline unsigned short f2b(float f) {
    __hip_bfloat16 h = __float2bfloat16(f);
    return *(unsigned short*)&h;
}
__device__ inline float b2f(unsigned short u) {
    union { unsigned i; float f; } v; v.i = ((unsigned)u) << 16; return v.f;
}

// device-scope relaxed atomics
__device__ inline double gloadd(const double* p) {
    return __hip_atomic_load(p, __ATOMIC_RELAXED, __HIP_MEMORY_SCOPE_AGENT);
}
__device__ inline void gstored(double* p, double v) {
    __hip_atomic_store(p, v, __ATOMIC_RELAXED, __HIP_MEMORY_SCOPE_AGENT);
}
__device__ inline void gatomicd(double* p, double v) {
    __hip_atomic_fetch_add(p, v, __ATOMIC_RELAXED, __HIP_MEMORY_SCOPE_AGENT);
}
__device__ inline unsigned long long gloadu64(const unsigned long long* p) {
    return __hip_atomic_load(p, __ATOMIC_RELAXED, __HIP_MEMORY_SCOPE_AGENT);
}
__device__ inline void gstoreu64(unsigned long long* p, unsigned long long v) {
    __hip_atomic_store(p, v, __ATOMIC_RELAXED, __HIP_MEMORY_SCOPE_AGENT);
}

// -------- precompute kernels (unchanged) --------

__global__ void build_wg(const float* __restrict__ Wiouh, const float* __restrict__ Wfh,
                         unsigned short* __restrict__ Wgb) {
    int k = blockIdx.y;
    int g = blockIdx.x * 256 + threadIdx.x;
    unsigned a = f2b(Wiouh[k * 3072 + g]);
    unsigned b = f2b(Wiouh[k * 3072 + 1024 + g]);
    unsigned c = f2b(Wiouh[k * 3072 + 2048 + g]);
    unsigned d = f2b(Wfh[k * 1024 + g]);
    uint2 p; p.x = a | (b << 16); p.y = c | (d << 16);
    *(uint2*)(Wgb + (size_t)k * 4096 + 4 * g) = p;
}

__global__ void transpose_g(const float* __restrict__ src, float* __restrict__ dst,
                            int R, int C) {
    __shared__ float tile[32][33];
    int c = blockIdx.x * 32 + threadIdx.x;
    int r0 = blockIdx.y * 32;
    for (int i = threadIdx.y; i < 32; i += 8)
        tile[i][threadIdx.x] = src[(size_t)(r0 + i) * C + c];
    __syncthreads();
    int r = r0 + threadIdx.x;
    int c0 = blockIdx.x * 32;
    for (int i = threadIdx.y; i < 32; i += 8)
        dst[(size_t)(c0 + i) * R + r] = tile[threadIdx.x][i];
}

__global__ __launch_bounds__(256) void gemm_bias(const float* __restrict__ A,
                                                 const float* __restrict__ B,
                                                 const float* __restrict__ b1,
                                                 const float* __restrict__ b2,
                                                 float* __restrict__ C,
                                                 int M, int N, int K, int tr) {
    __shared__ float As[16][68];
    __shared__ float Bs[16][68];
    int t = threadIdx.x;
    int m0 = blockIdx.y * 64, n0 = blockIdx.x * 64;
    int tx = t & 15, ty = t >> 4;
    float acc[4][4] = {};
    for (int kk = 0; kk < K; kk += 16) {
        {
            int m = t >> 2, k4 = (t & 3) * 4;
            const float4 a4 = *(const float4*)(A + (size_t)(m0 + m) * K + kk + k4);
            As[k4 + 0][m] = a4.x; As[k4 + 1][m] = a4.y;
            As[k4 + 2][m] = a4.z; As[k4 + 3][m] = a4.w;
            int kb = t >> 4, n = (t & 15) * 4;
            const float4 b4 = *(const float4*)(B + (size_t)(kk + kb) * N + n0 + n);
            *(float4*)&Bs[kb][n] = b4;
        }
        __syncthreads();
#pragma unroll
        for (int k = 0; k < 16; k++) {
            float a[4], b[4];
            *(float4*)a = *(const float4*)&As[k][ty * 4];
            *(float4*)b = *(const float4*)&Bs[k][tx * 4];
#pragma unroll
            for (int i = 0; i < 4; i++)
#pragma unroll
                for (int j = 0; j < 4; j++)
                    acc[i][j] = fmaf(a[i], b[j], acc[i][j]);
        }
        __syncthreads();
    }
#pragma unroll
    for (int i = 0; i < 4; i++) {
        int m = m0 + ty * 4 + i;
#pragma unroll
        for (int j = 0; j < 4; j++) {
            int n = n0 + tx * 4 + j;
            float v = acc[i][j];
            if (b1) v += b1[n];
            if (b2) v += b2[n];
            if (tr) C[(size_t)n * M + m] = v;
            else    C[(size_t)m * N + n] = v;
        }
    }
}

__global__ __launch_bounds__(256) void gemm_gi(const float* __restrict__ A,
                                               const float* __restrict__ B,
                                               unsigned short* __restrict__ Gb,
                                               int M, int N, int K, int cofs) {
    __shared__ float As[16][68];
    __shared__ float Bs[16][68];
    int t = threadIdx.x;
    int m0 = blockIdx.y * 64, n0 = blockIdx.x * 64;
    int tx = t & 15, ty = t >> 4;
    float acc[4][4] = {};
    for (int kk = 0; kk < K; kk += 16) {
        {
            int m = t >> 2, k4 = (t & 3) * 4;
            const float4 a4 = *(const float4*)(A + (size_t)(m0 + m) * K + kk + k4);
            As[k4 + 0][m] = a4.x; As[k4 + 1][m] = a4.y;
            As[k4 + 2][m] = a4.z; As[k4 + 3][m] = a4.w;
            int kb = t >> 4, n = (t & 15) * 4;
            const float4 b4 = *(const float4*)(B + (size_t)(kk + kb) * N + n0 + n);
            *(float4*)&Bs[kb][n] = b4;
        }
        __syncthreads();
#pragma unroll
        for (int k = 0; k < 16; k++) {
            float a[4], b[4];
            *(float4*)a = *(const float4*)&As[k][ty * 4];
            *(float4*)b = *(const float4*)&Bs[k][tx * 4];
#pragma unroll
            for (int i = 0; i < 4; i++)
#pragma unroll
                for (int j = 0; j < 4; j++)
                    acc[i][j] = fmaf(a[i], b[j], acc[i][j]);
        }
        __syncthreads();
    }
#pragma unroll
    for (int i = 0; i < 4; i++) {
        int m = m0 + ty * 4 + i;
#pragma unroll
        for (int j = 0; j < 4; j++) {
            int n = n0 + tx * 4 + j;
            int cp = 4 * (n & 1023) + (n >> 10) + cofs;
            Gb[(size_t)m * 4096 + cp] = f2b(acc[i][j]);
        }
    }
}

__global__ void colsum_k(const float* __restrict__ H, float* __restrict__ out) {
    int k = blockIdx.x * 256 + threadIdx.x;
    float s = 0.f;
#pragma unroll 8
    for (int r = 0; r < MROWS; r++) s += H[(size_t)r * MDIM + k];
    out[k] = s;
}

__global__ void hcolw_k(const float* __restrict__ Hcol,
                        const unsigned short* __restrict__ Wgb,
                        float* __restrict__ HcolW) {
    int j = blockIdx.x * 256 + threadIdx.x;
    float acc = 0.f;
#pragma unroll 8
    for (int k = 0; k < 1024; k++)
        acc = fmaf(Hcol[k], b2f(Wgb[(size_t)k * 4096 + j]), acc);
    HcolW[j] = acc;
}

__device__ inline float sum8(const float* s) {
    return s[0] + s[1] + s[2] + s[3] + s[4] + s[5] + s[6] + s[7];
}

// -------- persistent recurrent kernel --------
// R19 = R15 verbatim EXCEPT the score copies: [2][32][512] f64, 4
// sub-copies per XCD -> same-address RMW depth 8 (was 32). Fused
// count-bias detection preserved (detection == payload, ~1.5 RT).
//  * h: 4 producer threads store ONE 8B packet {f32 h, u32 epoch} each;
//    consumers poll the packet (detection == payload).
//  * score: block (x,y) adds into copy x*4+(y&3); consumer polls its
//    element's 32 copies until each > DONE_TH (8 adds arrived).
//  * zeroing: each block zeroes 64 doubles of the consumed buffer after
//    barrier #5 (all-256-epoch proof); drained by waitcnt before that
//    block's adds -> count-complete transitively proves zeroes visible.
__global__ __launch_bounds__(NTHR, 4) void recurrent(
    const unsigned short* __restrict__ Wgb, const float* __restrict__ WatT,
    const float* __restrict__ HpreT, const float* __restrict__ HT,
    const float* __restrict__ Hcol, const float* __restrict__ HcolW,
    const unsigned short* __restrict__ Gb, const float* __restrict__ X_iou,
    const float* __restrict__ X_f, const float* __restrict__ Wa,
    unsigned long long* hline, double* scored, float* out) {

    const int b = blockIdx.x, t = threadIdx.x;
    const int x = b & 7, y = b >> 3;          // XCD-contiguous slices
    const int g_col = x * 128 + y * 4;        // block's 4 output/attention columns
    const int j0 = x * 512 + y * 16;          // block's 16 interleaved gate cols
    const int cidx = x * 4 + (y & 3);         // this block's score sub-copy
    float creg = 0.f;                          // cell state (threads t<4)
    __shared__ float smem[2632];
    float* hs   = smem;          // 1056 padded h (current)
    float* le   = smem + 1056;   // 512 e
    float* red  = smem + 1568;   // [32][16] s1 partials (written in X overlap)
    float* red2 = smem + 2080;   // [32][16] s2 partials
    float* sred = smem + 2592;   // 8  (S partials)
    float* sred2= smem + 2600;   // 8  (P partials)
    float* dotb = smem + 2608;   // 16
    float* attr = smem + 2624;   // 8  (att_v reduction slots)

    const int jt = t & 15, kq = t >> 4;
    const int li = t & 127, tr = t >> 7;
    const int tl = t & 255, hi2 = t >> 8;     // h-poll: 2 threads per line

    // ---- hoist step-invariant loads into registers ----
    float wregf[32];
#pragma unroll
    for (int i = 0; i < 32; i++)
        wregf[i] = b2f(Wgb[(size_t)(kq * 32 + i) * 4096 + j0 + jt]);
    float gregf[16];
#pragma unroll
    for (int i = 0; i < 16; i++)
        gregf[i] = b2f(Gb[(size_t)(kq * 16 + i) * 4096 + j0 + jt]);
    const float* wr = WatT + (size_t)(g_col + tr) * 1024;
    float4 watv0 = *(const float4*)(wr + li * 4);
    float4 watv1 = *(const float4*)(wr + 512 + li * 4);
    float hpr[4], htr[4];
#pragma unroll
    for (int i = 0; i < 4; i++) {
        hpr[i] = HpreT[(size_t)(g_col + i) * 512 + t];
        htr[i] = HT[(size_t)(g_col + tr) * 512 + li + 128 * i];
    }
    const float hcw   = (t < 16) ? HcolW[j0 + t] : 0.f;
    const float hcolg = (t < 4) ? Hcol[g_col + t] : 0.f;
    const float wa0 = Wa[g_col + 0], wa1 = Wa[g_col + 1];
    const float wa2 = Wa[g_col + 2], wa3 = Wa[g_col + 3];

    // ---- prime: s1 partials = 0 for step 0 (hs fully written in X(0)) ----
    red[kq * 16 + jt] = 0.f;

    for (int st = 0; st < T_STEPS; st++) {
        // ---- Y: e (poll 32 strided copies) + gates + h packet + out ----
        float xi0 = 0.f, xi1 = 0.f, xi2 = 0.f, xf0 = 0.f;
        if (t < 4) {                      // issued before poll: latency hidden
            int g = g_col + t;
            xi0 = X_iou[(size_t)st * 3072 + g];
            xi1 = X_iou[(size_t)st * 3072 + 1024 + g];
            xi2 = X_iou[(size_t)st * 3072 + 2048 + g];
            xf0 = X_f[(size_t)st * 1024 + g];
        }
        float sc = 0.f;
        if (st > 0) {
            const double* sp = scored + (size_t)((st + 1) & 1) * 16384 + t;
            double vv[32];
            for (;;) {
                bool ok = true;
#pragma unroll
                for (int c = 0; c < 32; c++) {
                    vv[c] = gloadd(sp + c * 512);
                    ok = ok && (vv[c] > DONE_TH);
                }
                if (ok) break;
                __builtin_amdgcn_s_sleep(1);
            }
            double accd = 0.0;
#pragma unroll
            for (int c = 0; c < 32; c++) accd += (vv[c] - SUBBIAS);
            sc = (float)accd;
        }
        float evv = __expf(sc);
        le[t] = evv;
        float sv = wave_red(evv);
        if ((t & 63) == 0) sred[t >> 6] = sv;
        __syncthreads();                       // #1
        // s2 (G-correction) from registers
        float a2 = 0.f;
#pragma unroll
        for (int i = 0; i < 16; i++)
            a2 = fmaf(le[kq * 16 + i], gregf[i], a2);
        red2[kq * 16 + jt] = a2;
        // P for block's 4 out-cols
        float pp = 0.f;
#pragma unroll
        for (int i = 0; i < 4; i++)
            pp = fmaf(le[li + 128 * i], htr[i], pp);
        pp = wave_red(pp);
        if ((t & 63) == 0) sred2[t >> 6] = pp;
        __syncthreads();                       // #2
        if (t < 16) {                          // wave-0 writes dotb...
            float s1 = 0.f, s2 = 0.f;
#pragma unroll
            for (int q = 0; q < 32; q++) { s1 += red[q * 16 + t]; s2 += red2[q * 16 + t]; }
            float S = sum8(sred);
            float invS = (st == 0) ? 0.f : 1.f / S;
            float hw = (st == 0) ? 0.f : hcw;
            dotb[t] = s1 + hw - invS * s2;
        }
        if (t < 4) {                           // ...read also wave-0: in-order LDS
            int g = g_col + t;
            if (st > 0) {
                float S = sum8(sred);
                float P = sred2[t * 2] + sred2[t * 2 + 1];
                out[(size_t)(st - 1) * 1024 + g] =
                    hcolg + hs[g + (g >> 5)] - P / S;
            }
            float di = dotb[t * 4 + 0] + xi0;
            float doo = dotb[t * 4 + 1] + xi1;
            float du = dotb[t * 4 + 2] + xi2;
            float df = dotb[t * 4 + 3] + xf0;
            float ig = sigm(di), og = sigm(doo), fg = sigm(df);
            float ug = fast_tanh(du);
            creg = ig * ug + fg * creg;
            float hv = og * fast_tanh(creg);
            // fused payload+flag: one 8B single-copy-atomic packet
            unsigned long long pkt =
                ((unsigned long long)(unsigned)(st + 1) << 32) | __float_as_uint(hv);
            gstoreu64(hline + (size_t)b * 8 + t, pkt);
        }
        __syncthreads();                       // #4: hs rewritten in X below

        // ---- X: poll-with-payload h -> LDS, att_v, biased f64 adds ----
        {
            const unsigned long long* lp = hline + (size_t)tl * 8 + hi2 * 2;
            const unsigned tgt = (unsigned)(st + 1);
            unsigned long long u0, u1;
            for (;;) {
                u0 = gloadu64(lp);
                u1 = gloadu64(lp + 1);
                if ((unsigned)(u0 >> 32) >= tgt && (unsigned)(u1 >> 32) >= tgt) break;
                __builtin_amdgcn_s_sleep(1);
            }
            int gc = (tl & 7) * 128 + (tl >> 3) * 4 + hi2 * 2;
            union { unsigned u; float f; } c0, c1;
            c0.u = (unsigned)u0; c1.u = (unsigned)u1;
            hs[gc + (gc >> 5)] = c0.f;
            int g1 = gc + 1; hs[g1 + (g1 >> 5)] = c1.f;
        }
        __syncthreads();                       // #5: hs ready AND all 256 lines
                                               // verified >= st+1 block-wide
        // zero the buffer all Y(st) consumed: safe after #5 (every block has
        // passed its Y(st) reads, proven by the 256 epochs). 64 doubles per
        // block cover the 16384-double buffer exactly once.
        if (t < 64)
            gstored(scored + (size_t)((st + 1) & 1) * 16384 + (size_t)b * 64 + t, 0.0);
        {
            float acc = 0.f;
#pragma unroll
            for (int i = 0; i < 4; i++) {
                int k = li * 4 + i;
                acc = fmaf(((const float*)&watv0)[i], hs[k + (k >> 5)], acc);
                int k2 = 512 + li * 4 + i;
                acc = fmaf(((const float*)&watv1)[i], hs[k2 + (k2 >> 5)], acc);
            }
            acc = wave_red(acc);
            if ((t & 63) == 0) attr[t >> 6] = acc;
            __syncthreads();                   // #6 (implicit vmcnt(0): zeroes)
            float av0 = attr[0] + attr[1], av1 = attr[2] + attr[3];
            float av2 = attr[4] + attr[5], av3 = attr[6] + attr[7];
            float ps = wa0 * fast_tanh(hpr[0] + av0)
                     + wa1 * fast_tanh(hpr[1] + av1)
                     + wa2 * fast_tanh(hpr[2] + av2)
                     + wa3 * fast_tanh(hpr[3] + av3);
            __asm__ volatile("" ::: "memory");
            __builtin_amdgcn_s_waitcnt(0);     // own zero-stores drained first
            gatomicd(scored + (size_t)(st & 1) * 16384 + (size_t)cidx * 512 + t,
                     (double)ps + BIAS32);
        }
        // s1 overlap for next step's gates (runs under the exchange latency)
        {
            float a = 0.f;
#pragma unroll
            for (int i = 0; i < 32; i++) {
                int k = kq * 32 + i;
                a = fmaf(hs[k + (k >> 5)], wregf[i], a);
            }
            red[kq * 16 + jt] = a;
        }
    }

    // ---- Epilogue: out[T-1] (Y(T) without gates) ----
    {
        const double* sp = scored + (size_t)((T_STEPS + 1) & 1) * 16384 + t;
        double vv[32];
        for (;;) {
            bool ok = true;
#pragma unroll
            for (int c = 0; c < 32; c++) {
                vv[c] = gloadd(sp + c * 512);
                ok = ok && (vv[c] > DONE_TH);
            }
            if (ok) break;
            __builtin_amdgcn_s_sleep(1);
        }
        double accd = 0.0;
#pragma unroll
        for (int c = 0; c < 32; c++) accd += (vv[c] - SUBBIAS);
        float evv = __expf((float)accd);
        le[t] = evv;
        float sv = wave_red(evv);
        if ((t & 63) == 0) sred[t >> 6] = sv;
        __syncthreads();
        float pp = 0.f;
#pragma unroll
        for (int i = 0; i < 4; i++)
            pp = fmaf(le[li + 128 * i], htr[i], pp);
        pp = wave_red(pp);
        if ((t & 63) == 0) sred2[t >> 6] = pp;
        __syncthreads();
        if (t < 4) {
            int g = g_col + t;
            float S = sum8(sred);
            float P = sred2[t * 2] + sred2[t * 2 + 1];
            out[(size_t)(T_STEPS - 1) * 1024 + g] =
                hcolg + hs[g + (g >> 5)] - P / S;   // hs = h(T-1) from X(T-1)
        }
    }
}

extern "C" void kernel_launch(void* const* d_in, const int* in_sizes, int n_in,
                              void* d_out, int out_size, void* d_ws, size_t ws_size,
                              hipStream_t stream) {
    const float* inputs  = (const float*)d_in[0];
    const float* hiddn   = (const float*)d_in[1];
    const float* W_ioux  = (const float*)d_in[2];
    const float* b_ioux  = (const float*)d_in[3];
    const float* W_iouh  = (const float*)d_in[4];
    const float* b_iouh  = (const float*)d_in[5];
    const float* W_fx    = (const float*)d_in[6];
    const float* b_fx    = (const float*)d_in[7];
    const float* W_fh    = (const float*)d_in[8];
    const float* b_fh    = (const float*)d_in[9];
    const float* Wa      = (const float*)d_in[10];
    const float* W_attnh = (const float*)d_in[11];
    const float* b_attnh = (const float*)d_in[12];

    float* ws = (float*)d_ws;
    unsigned short* Wgb = (unsigned short*)(ws + OFF_WGB);
    float* WatT  = ws + OFF_WATT;
    float* HpreT = ws + OFF_HPRET;
    float* X_iou = ws + OFF_XIOU;
    float* X_f   = ws + OFF_XF;
    unsigned short* Gb = (unsigned short*)(ws + OFF_G);
    float* HT    = ws + OFF_HT;
    float* Hcol  = ws + OFF_HCOL;
    float* HcolW = ws + OFF_HCOLW;
    double* scored = (double*)(ws + OFF_SCORED);
    unsigned long long* hline = (unsigned long long*)(ws + OFF_HLINE);
    float* out   = (float*)d_out;

    // zero score copies (2x16384 f64 = 65536 floats) + hline (4096 floats)
    hipMemsetAsync(ws + OFF_SCORED, 0, (65536 + 4096) * sizeof(float), stream);

    build_wg<<<dim3(4, 1024), 256, 0, stream>>>(W_iouh, W_fh, Wgb);
    transpose_g<<<dim3(32, 32), dim3(32, 8), 0, stream>>>(W_attnh, WatT, 1024, 1024);
    transpose_g<<<dim3(32, 16), dim3(32, 8), 0, stream>>>(hiddn, HT, 512, 1024);
    gemm_bias<<<dim3(48, 4), 256, 0, stream>>>(inputs, W_ioux, b_ioux, b_iouh, X_iou, 256, 3072, 1024, 0);
    gemm_bias<<<dim3(16, 4), 256, 0, stream>>>(inputs, W_fx, b_fx, b_fh, X_f, 256, 1024, 1024, 0);
    gemm_bias<<<dim3(16, 8), 256, 0, stream>>>(hiddn, W_attnh + 1024 * 1024, b_attnh, nullptr, HpreT, 512, 1024, 1024, 1);
    colsum_k<<<4, 256, 0, stream>>>(hiddn, Hcol);
    hcolw_k<<<16, 256, 0, stream>>>(Hcol, Wgb, HcolW);
    gemm_gi<<<dim3(48, 8), 256, 0, stream>>>(hiddn, W_iouh, Gb, 512, 3072, 1024, 0);
    gemm_gi<<<dim3(16, 8), 256, 0, stream>>>(hiddn, W_fh, Gb, 512, 1024, 1024, 3);

    recurrent<<<GRID, NTHR, 0, stream>>>(Wgb, WatT, HpreT, HT, Hcol, HcolW, Gb,
                                         X_iou, X_f, Wa, hline, scored, out);
}

// Round 8
// 1762.964 us; speedup vs baseline: 2.7112x; 2.7112x over previous
//
#include <hip/hip_runtime.h>
#include <hip/hip_bf16.h>

// ---------------- sizes ----------------
#define T_STEPS 256
#define MDIM 1024
#define MROWS 512
#define NBLK 128
#define GRID NBLK
#define NTHR 512

// ws float offsets
#define OFF_WGB     0u                      // bf16 [1024][4096] interleaved gates (2M floats)
#define OFF_WATT    2097152u                // fp32 [1024][1024] W_attnh top, transposed
#define OFF_HPRET   3145728u                // fp32 [1024][512]  Hpre TRANSPOSED
#define OFF_XIOU    3670016u                // fp32 [256][3072]
#define OFF_XF      4456448u                // fp32 [256][1024]
#define OFF_G       4718592u                // bf16 [512][4096]  G = H @ Wg
#define OFF_HT      5767168u                // fp32 [1024][512]  H transposed
#define OFF_HCOL    6291456u                // fp32 [1024]
#define OFF_HCOLW   6292480u                // fp32 [4096]  Hcol @ Wg
#define OFF_SCORED  6297600u                // f64 [2][8][512] count-biased score copies, COPY-MAJOR (zeroed)
#define OFF_HLINE   6313984u                // u64 [128][8]: 8 packets {f32 h, u32 epoch} per block (zeroed)

// R20 = R15 rescaled to 128 blocks x 8 columns. Same exchange topology
// (narrow polls, fused flag-in-payload, copy-major single-XCD atomic
// lines) -- every participant-scaled term halves: h-poll agents
// 131K->65K, h-lines 256->128, score RMW depth 32->16, straggler set
// 256->128. No idle blocks (R17's failure mode).
// Copy x of element t gets 16 adds (blocks with b&7==x, one XCD).
// Settled = 16*BIAS32 + partial; de-bias SUBBIAS=2^36 (Sterbenz-exact).
#define BIAS32  4294967296.0                // 2^32
#define SUBBIAS (16.0 * 4294967296.0)       // 2^36
#define DONE_TH (16.0 * 4294967296.0 - 1073741824.0)   // 16*2^32 - 2^30

__device__ inline float fast_tanh(float v) {
    float x = fminf(fmaxf(v, -15.f), 15.f);
    float z = __expf(2.f * x);
    return (z - 1.f) / (z + 1.f);
}
__device__ inline float sigm(float v) { return 1.f / (1.f + __expf(-v)); }

__device__ inline float wave_red(float v) {
#pragma unroll
    for (int s = 32; s > 0; s >>= 1) v += __shfl_down(v, s, 64);
    return v;
}

__device__ __host__ inline unsigned short f2b(float f) {
    __hip_bfloat16 h = __float2bfloat16(f);
    return *(unsigned short*)&h;
}
__device__ inline float b2f(unsigned short u) {
    union { unsigned i; float f; } v; v.i = ((unsigned)u) << 16; return v.f;
}

// device-scope relaxed atomics
__device__ inline double gloadd(const double* p) {
    return __hip_atomic_load(p, __ATOMIC_RELAXED, __HIP_MEMORY_SCOPE_AGENT);
}
__device__ inline void gstored(double* p, double v) {
    __hip_atomic_store(p, v, __ATOMIC_RELAXED, __HIP_MEMORY_SCOPE_AGENT);
}
__device__ inline void gatomicd(double* p, double v) {
    __hip_atomic_fetch_add(p, v, __ATOMIC_RELAXED, __HIP_MEMORY_SCOPE_AGENT);
}
__device__ inline unsigned long long gloadu64(const unsigned long long* p) {
    return __hip_atomic_load(p, __ATOMIC_RELAXED, __HIP_MEMORY_SCOPE_AGENT);
}
__device__ inline void gstoreu64(unsigned long long* p, unsigned long long v) {
    __hip_atomic_store(p, v, __ATOMIC_RELAXED, __HIP_MEMORY_SCOPE_AGENT);
}

// -------- precompute kernels (unchanged) --------

__global__ void build_wg(const float* __restrict__ Wiouh, const float* __restrict__ Wfh,
                         unsigned short* __restrict__ Wgb) {
    int k = blockIdx.y;
    int g = blockIdx.x * 256 + threadIdx.x;
    unsigned a = f2b(Wiouh[k * 3072 + g]);
    unsigned b = f2b(Wiouh[k * 3072 + 1024 + g]);
    unsigned c = f2b(Wiouh[k * 3072 + 2048 + g]);
    unsigned d = f2b(Wfh[k * 1024 + g]);
    uint2 p; p.x = a | (b << 16); p.y = c | (d << 16);
    *(uint2*)(Wgb + (size_t)k * 4096 + 4 * g) = p;
}

__global__ void transpose_g(const float* __restrict__ src, float* __restrict__ dst,
                            int R, int C) {
    __shared__ float tile[32][33];
    int c = blockIdx.x * 32 + threadIdx.x;
    int r0 = blockIdx.y * 32;
    for (int i = threadIdx.y; i < 32; i += 8)
        tile[i][threadIdx.x] = src[(size_t)(r0 + i) * C + c];
    __syncthreads();
    int r = r0 + threadIdx.x;
    int c0 = blockIdx.x * 32;
    for (int i = threadIdx.y; i < 32; i += 8)
        dst[(size_t)(c0 + i) * R + r] = tile[threadIdx.x][i];
}

__global__ __launch_bounds__(256) void gemm_bias(const float* __restrict__ A,
                                                 const float* __restrict__ B,
                                                 const float* __restrict__ b1,
                                                 const float* __restrict__ b2,
                                                 float* __restrict__ C,
                                                 int M, int N, int K, int tr) {
    __shared__ float As[16][68];
    __shared__ float Bs[16][68];
    int t = threadIdx.x;
    int m0 = blockIdx.y * 64, n0 = blockIdx.x * 64;
    int tx = t & 15, ty = t >> 4;
    float acc[4][4] = {};
    for (int kk = 0; kk < K; kk += 16) {
        {
            int m = t >> 2, k4 = (t & 3) * 4;
            const float4 a4 = *(const float4*)(A + (size_t)(m0 + m) * K + kk + k4);
            As[k4 + 0][m] = a4.x; As[k4 + 1][m] = a4.y;
            As[k4 + 2][m] = a4.z; As[k4 + 3][m] = a4.w;
            int kb = t >> 4, n = (t & 15) * 4;
            const float4 b4 = *(const float4*)(B + (size_t)(kk + kb) * N + n0 + n);
            *(float4*)&Bs[kb][n] = b4;
        }
        __syncthreads();
#pragma unroll
        for (int k = 0; k < 16; k++) {
            float a[4], b[4];
            *(float4*)a = *(const float4*)&As[k][ty * 4];
            *(float4*)b = *(const float4*)&Bs[k][tx * 4];
#pragma unroll
            for (int i = 0; i < 4; i++)
#pragma unroll
                for (int j = 0; j < 4; j++)
                    acc[i][j] = fmaf(a[i], b[j], acc[i][j]);
        }
        __syncthreads();
    }
#pragma unroll
    for (int i = 0; i < 4; i++) {
        int m = m0 + ty * 4 + i;
#pragma unroll
        for (int j = 0; j < 4; j++) {
            int n = n0 + tx * 4 + j;
            float v = acc[i][j];
            if (b1) v += b1[n];
            if (b2) v += b2[n];
            if (tr) C[(size_t)n * M + m] = v;
            else    C[(size_t)m * N + n] = v;
        }
    }
}

__global__ __launch_bounds__(256) void gemm_gi(const float* __restrict__ A,
                                               const float* __restrict__ B,
                                               unsigned short* __restrict__ Gb,
                                               int M, int N, int K, int cofs) {
    __shared__ float As[16][68];
    __shared__ float Bs[16][68];
    int t = threadIdx.x;
    int m0 = blockIdx.y * 64, n0 = blockIdx.x * 64;
    int tx = t & 15, ty = t >> 4;
    float acc[4][4] = {};
    for (int kk = 0; kk < K; kk += 16) {
        {
            int m = t >> 2, k4 = (t & 3) * 4;
            const float4 a4 = *(const float4*)(A + (size_t)(m0 + m) * K + kk + k4);
            As[k4 + 0][m] = a4.x; As[k4 + 1][m] = a4.y;
            As[k4 + 2][m] = a4.z; As[k4 + 3][m] = a4.w;
            int kb = t >> 4, n = (t & 15) * 4;
            const float4 b4 = *(const float4*)(B + (size_t)(kk + kb) * N + n0 + n);
            *(float4*)&Bs[kb][n] = b4;
        }
        __syncthreads();
#pragma unroll
        for (int k = 0; k < 16; k++) {
            float a[4], b[4];
            *(float4*)a = *(const float4*)&As[k][ty * 4];
            *(float4*)b = *(const float4*)&Bs[k][tx * 4];
#pragma unroll
            for (int i = 0; i < 4; i++)
#pragma unroll
                for (int j = 0; j < 4; j++)
                    acc[i][j] = fmaf(a[i], b[j], acc[i][j]);
        }
        __syncthreads();
    }
#pragma unroll
    for (int i = 0; i < 4; i++) {
        int m = m0 + ty * 4 + i;
#pragma unroll
        for (int j = 0; j < 4; j++) {
            int n = n0 + tx * 4 + j;
            int cp = 4 * (n & 1023) + (n >> 10) + cofs;
            Gb[(size_t)m * 4096 + cp] = f2b(acc[i][j]);
        }
    }
}

__global__ void colsum_k(const float* __restrict__ H, float* __restrict__ out) {
    int k = blockIdx.x * 256 + threadIdx.x;
    float s = 0.f;
#pragma unroll 8
    for (int r = 0; r < MROWS; r++) s += H[(size_t)r * MDIM + k];
    out[k] = s;
}

__global__ void hcolw_k(const float* __restrict__ Hcol,
                        const unsigned short* __restrict__ Wgb,
                        float* __restrict__ HcolW) {
    int j = blockIdx.x * 256 + threadIdx.x;
    float acc = 0.f;
#pragma unroll 8
    for (int k = 0; k < 1024; k++)
        acc = fmaf(Hcol[k], b2f(Wgb[(size_t)k * 4096 + j]), acc);
    HcolW[j] = acc;
}

__device__ inline float sum8(const float* s) {
    return s[0] + s[1] + s[2] + s[3] + s[4] + s[5] + s[6] + s[7];
}

// -------- persistent recurrent kernel --------
// R20: R15's exact phase/barrier/ordering structure at 128 blocks.
// Block (x=b&7, y=b>>3<16): 8 output/att cols g_col..g_col+7,
// 32 interleaved gate cols j0..j0+31, 8 h packets in one 64B hline.
//  * h: t<8 store {f32 h, u32 epoch} packets; consumers: 4 thr/line
//    poll 2 packets each (detection == payload).
//  * score: f64 count-bias atomics into copy x (depth 16, single-XCD
//    lines); consumer thread polls its element's 8 copies.
//  * zeroing after barrier #5 (all-128-epoch proof), drained by #6's
//    implicit vmcnt(0) + explicit waitcnt before this block's adds.
__global__ __launch_bounds__(NTHR, 2) void recurrent(
    const unsigned short* __restrict__ Wgb, const float* __restrict__ WatT,
    const float* __restrict__ HpreT, const float* __restrict__ HT,
    const float* __restrict__ Hcol, const float* __restrict__ HcolW,
    const unsigned short* __restrict__ Gb, const float* __restrict__ X_iou,
    const float* __restrict__ X_f, const float* __restrict__ Wa,
    unsigned long long* hline, double* scored, float* out) {

    const int b = blockIdx.x, t = threadIdx.x;
    const int x = b & 7, y = b >> 3;          // y in [0,16)
    const int g_col = x * 128 + y * 8;        // block's 8 output/attention cols
    const int j0 = x * 512 + y * 32;          // block's 32 interleaved gate cols
    float creg = 0.f;                          // cell state (threads t<8)
    __shared__ float smem[2648];
    float* hs   = smem;          // 1056 padded h (current)
    float* le   = smem + 1056;   // 512 e
    float* red  = smem + 1568;   // [16][32] s1 partials (written in X overlap)
    float* red2 = smem + 2080;   // [16][32] s2 partials
    float* sred = smem + 2592;   // 8  (S partials, 1/wave)
    float* sred2= smem + 2600;   // 8  (P per col, 1/wave)
    float* dotb = smem + 2608;   // 32
    float* attr = smem + 2640;   // 8  (att_v per col, 1/wave)

    const int jt = t & 31, kq = t >> 5;       // gates: 16 k-groups x 32 cols
    const int li = t & 63, tr = t >> 6;       // lane, wave id (0..7)
    const int tl = t & 127, hi = t >> 7;      // h-poll: 4 thr/line, 2 packets

    // ---- hoist step-invariant loads into registers ----
    float wregf[64];
#pragma unroll
    for (int i = 0; i < 64; i++)
        wregf[i] = b2f(Wgb[(size_t)(kq * 64 + i) * 4096 + j0 + jt]);
    float gregf[32];
#pragma unroll
    for (int i = 0; i < 32; i++)
        gregf[i] = b2f(Gb[(size_t)(kq * 32 + i) * 4096 + j0 + jt]);
    float watreg[16];
#pragma unroll
    for (int i = 0; i < 16; i++)
        watreg[i] = WatT[(size_t)(g_col + tr) * 1024 + i * 64 + li];
    float htr[8], hpr[8], wa8[8];
#pragma unroll
    for (int i = 0; i < 8; i++)
        htr[i] = HT[(size_t)(g_col + tr) * 512 + li + 64 * i];
#pragma unroll
    for (int c = 0; c < 8; c++) {
        hpr[c] = HpreT[(size_t)(g_col + c) * 512 + t];
        wa8[c] = Wa[g_col + c];
    }
    const float hcw   = (t < 32) ? HcolW[j0 + t] : 0.f;
    const float hcolg = (t < 8) ? Hcol[g_col + t] : 0.f;

    // ---- prime: s1 partials = 0 for step 0 (hs fully written in X(0)) ----
    red[kq * 32 + jt] = 0.f;

    for (int st = 0; st < T_STEPS; st++) {
        // ---- Y: e (poll 8 strided copies) + gates + h packets + out ----
        float xi0 = 0.f, xi1 = 0.f, xi2 = 0.f, xf0 = 0.f;
        if (t < 8) {                      // issued before poll: latency hidden
            int g = g_col + t;
            xi0 = X_iou[(size_t)st * 3072 + g];
            xi1 = X_iou[(size_t)st * 3072 + 1024 + g];
            xi2 = X_iou[(size_t)st * 3072 + 2048 + g];
            xf0 = X_f[(size_t)st * 1024 + g];
        }
        float sc = 0.f;
        if (st > 0) {
            const double* sp = scored + (size_t)((st + 1) & 1) * 4096 + t;
            double vv[8];
            for (;;) {
                bool ok = true;
#pragma unroll
                for (int c = 0; c < 8; c++) {
                    vv[c] = gloadd(sp + c * 512);
                    ok = ok && (vv[c] > DONE_TH);
                }
                if (ok) break;
                __builtin_amdgcn_s_sleep(1);
            }
            double accd = 0.0;
#pragma unroll
            for (int c = 0; c < 8; c++) accd += (vv[c] - SUBBIAS);
            sc = (float)accd;
        }
        float evv = __expf(sc);
        le[t] = evv;
        float sv = wave_red(evv);
        if ((t & 63) == 0) sred[t >> 6] = sv;
        __syncthreads();                       // #1
        // s2 (G-correction) from registers: rows kq*32+i
        float a2 = 0.f;
#pragma unroll
        for (int i = 0; i < 32; i++)
            a2 = fmaf(le[kq * 32 + i], gregf[i], a2);
        red2[kq * 32 + jt] = a2;
        // P for block's 8 out-cols: wave tr owns col g_col+tr
        float pp = 0.f;
#pragma unroll
        for (int i = 0; i < 8; i++)
            pp = fmaf(le[li + 64 * i], htr[i], pp);
        pp = wave_red(pp);
        if ((t & 63) == 0) sred2[t >> 6] = pp;
        __syncthreads();                       // #2
        if (t < 32) {                          // wave-0 writes dotb...
            float s1 = 0.f, s2 = 0.f;
#pragma unroll
            for (int q = 0; q < 16; q++) { s1 += red[q * 32 + t]; s2 += red2[q * 32 + t]; }
            float S = sum8(sred);
            float invS = (st == 0) ? 0.f : 1.f / S;
            float hw = (st == 0) ? 0.f : hcw;
            dotb[t] = s1 + hw - invS * s2;
        }
        if (t < 8) {                           // ...read also wave-0: in-order LDS
            int g = g_col + t;
            if (st > 0) {
                float S = sum8(sred);
                float P = sred2[t];
                out[(size_t)(st - 1) * 1024 + g] =
                    hcolg + hs[g + (g >> 5)] - P / S;
            }
            float di = dotb[t * 4 + 0] + xi0;
            float doo = dotb[t * 4 + 1] + xi1;
            float du = dotb[t * 4 + 2] + xi2;
            float df = dotb[t * 4 + 3] + xf0;
            float ig = sigm(di), og = sigm(doo), fg = sigm(df);
            float ug = fast_tanh(du);
            creg = ig * ug + fg * creg;
            float hv = og * fast_tanh(creg);
            // fused payload+flag: one 8B single-copy-atomic packet
            unsigned long long pkt =
                ((unsigned long long)(unsigned)(st + 1) << 32) | __float_as_uint(hv);
            gstoreu64(hline + (size_t)b * 8 + t, pkt);
        }
        __syncthreads();                       // #4: hs rewritten in X below

        // ---- X: poll-with-payload h -> LDS, att_v, biased f64 adds ----
        {
            const unsigned long long* lp = hline + (size_t)tl * 8 + hi * 2;
            const unsigned tgt = (unsigned)(st + 1);
            unsigned long long u0, u1;
            for (;;) {
                u0 = gloadu64(lp);
                u1 = gloadu64(lp + 1);
                if ((unsigned)(u0 >> 32) >= tgt && (unsigned)(u1 >> 32) >= tgt) break;
                __builtin_amdgcn_s_sleep(1);
            }
            int gc = (tl & 7) * 128 + (tl >> 3) * 8 + hi * 2;
            union { unsigned u; float f; } c0, c1;
            c0.u = (unsigned)u0; c1.u = (unsigned)u1;
            hs[gc + (gc >> 5)] = c0.f;
            int g1 = gc + 1; hs[g1 + (g1 >> 5)] = c1.f;
        }
        __syncthreads();                       // #5: hs ready AND all 128 lines
                                               // verified >= st+1 block-wide
        // zero the buffer all Y(st) consumed: safe after #5 (every block has
        // passed its Y(st) reads, proven by the 128 epochs). 32 doubles per
        // block cover the 4096-double buffer exactly once.
        if (t < 32)
            gstored(scored + (size_t)((st + 1) & 1) * 4096 + (size_t)b * 32 + t, 0.0);
        {
            // att_v: wave tr computes col g_col+tr (16 fma/lane from hs)
            float acc = 0.f;
#pragma unroll
            for (int i = 0; i < 16; i++) {
                int k = i * 64 + li;
                acc = fmaf(watreg[i], hs[k + (k >> 5)], acc);
            }
            acc = wave_red(acc);
            if ((t & 63) == 0) attr[t >> 6] = acc;
            __syncthreads();                   // #6 (implicit vmcnt(0): zeroes)
            float ps = 0.f;
#pragma unroll
            for (int c = 0; c < 8; c++)
                ps = fmaf(wa8[c], fast_tanh(hpr[c] + attr[c]), ps);
            __asm__ volatile("" ::: "memory");
            __builtin_amdgcn_s_waitcnt(0);     // own zero-store drained first
            gatomicd(scored + (size_t)(st & 1) * 4096 + x * 512 + t,
                     (double)ps + BIAS32);
        }
        // s1 overlap for next step's gates (runs under the exchange latency)
        {
            float a = 0.f;
#pragma unroll
            for (int i = 0; i < 64; i++) {
                int k = kq * 64 + i;
                a = fmaf(hs[k + (k >> 5)], wregf[i], a);
            }
            red[kq * 32 + jt] = a;
        }
    }

    // ---- Epilogue: out[T-1] (Y(T) without gates) ----
    {
        const double* sp = scored + (size_t)((T_STEPS + 1) & 1) * 4096 + t;
        double vv[8];
        for (;;) {
            bool ok = true;
#pragma unroll
            for (int c = 0; c < 8; c++) {
                vv[c] = gloadd(sp + c * 512);
                ok = ok && (vv[c] > DONE_TH);
            }
            if (ok) break;
            __builtin_amdgcn_s_sleep(1);
        }
        double accd = 0.0;
#pragma unroll
        for (int c = 0; c < 8; c++) accd += (vv[c] - SUBBIAS);
        float evv = __expf((float)accd);
        le[t] = evv;
        float sv = wave_red(evv);
        if ((t & 63) == 0) sred[t >> 6] = sv;
        __syncthreads();
        float pp = 0.f;
#pragma unroll
        for (int i = 0; i < 8; i++)
            pp = fmaf(le[li + 64 * i], htr[i], pp);
        pp = wave_red(pp);
        if ((t & 63) == 0) sred2[t >> 6] = pp;
        __syncthreads();
        if (t < 8) {
            int g = g_col + t;
            float S = sum8(sred);
            float P = sred2[t];
            out[(size_t)(T_STEPS - 1) * 1024 + g] =
                hcolg + hs[g + (g >> 5)] - P / S;   // hs = h(T-1) from X(T-1)
        }
    }
}

extern "C" void kernel_launch(void* const* d_in, const int* in_sizes, int n_in,
                              void* d_out, int out_size, void* d_ws, size_t ws_size,
                              hipStream_t stream) {
    const float* inputs  = (const float*)d_in[0];
    const float* hiddn   = (const float*)d_in[1];
    const float* W_ioux  = (const float*)d_in[2];
    const float* b_ioux  = (const float*)d_in[3];
    const float* W_iouh  = (const float*)d_in[4];
    const float* b_iouh  = (const float*)d_in[5];
    const float* W_fx    = (const float*)d_in[6];
    const float* b_fx    = (const float*)d_in[7];
    const float* W_fh    = (const float*)d_in[8];
    const float* b_fh    = (const float*)d_in[9];
    const float* Wa      = (const float*)d_in[10];
    const float* W_attnh = (const float*)d_in[11];
    const float* b_attnh = (const float*)d_in[12];

    float* ws = (float*)d_ws;
    unsigned short* Wgb = (unsigned short*)(ws + OFF_WGB);
    float* WatT  = ws + OFF_WATT;
    float* HpreT = ws + OFF_HPRET;
    float* X_iou = ws + OFF_XIOU;
    float* X_f   = ws + OFF_XF;
    unsigned short* Gb = (unsigned short*)(ws + OFF_G);
    float* HT    = ws + OFF_HT;
    float* Hcol  = ws + OFF_HCOL;
    float* HcolW = ws + OFF_HCOLW;
    double* scored = (double*)(ws + OFF_SCORED);
    unsigned long long* hline = (unsigned long long*)(ws + OFF_HLINE);
    float* out   = (float*)d_out;

    // zero score copies (2x4096 f64 = 16384 floats) + hline (128x8 u64 = 2048 floats)
    hipMemsetAsync(ws + OFF_SCORED, 0, (16384 + 2048) * sizeof(float), stream);

    build_wg<<<dim3(4, 1024), 256, 0, stream>>>(W_iouh, W_fh, Wgb);
    transpose_g<<<dim3(32, 32), dim3(32, 8), 0, stream>>>(W_attnh, WatT, 1024, 1024);
    transpose_g<<<dim3(32, 16), dim3(32, 8), 0, stream>>>(hiddn, HT, 512, 1024);
    gemm_bias<<<dim3(48, 4), 256, 0, stream>>>(inputs, W_ioux, b_ioux, b_iouh, X_iou, 256, 3072, 1024, 0);
    gemm_bias<<<dim3(16, 4), 256, 0, stream>>>(inputs, W_fx, b_fx, b_fh, X_f, 256, 1024, 1024, 0);
    gemm_bias<<<dim3(16, 8), 256, 0, stream>>>(hiddn, W_attnh + 1024 * 1024, b_attnh, nullptr, HpreT, 512, 1024, 1024, 1);
    colsum_k<<<4, 256, 0, stream>>>(hiddn, Hcol);
    hcolw_k<<<16, 256, 0, stream>>>(Hcol, Wgb, HcolW);
    gemm_gi<<<dim3(48, 8), 256, 0, stream>>>(hiddn, W_iouh, Gb, 512, 3072, 1024, 0);
    gemm_gi<<<dim3(16, 8), 256, 0, stream>>>(hiddn, W_fh, Gb, 512, 1024, 1024, 3);

    recurrent<<<GRID, NTHR, 0, stream>>>(Wgb, WatT, HpreT, HT, Hcol, HcolW, Gb,
                                         X_iou, X_f, Wa, hline, scored, out);
}

// Round 9
// 1577.065 us; speedup vs baseline: 3.0308x; 1.1179x over previous
//
#include <hip/hip_runtime.h>
#include <hip/hip_bf16.h>

// ---------------- sizes ----------------
#define T_STEPS 256
#define MDIM 1024
#define MROWS 512
#define NBLK 128
#define GRID NBLK
#define NTHR 512

// ws float offsets
#define OFF_WGB     0u                      // bf16 [1024][4096] interleaved gates (2M floats)
#define OFF_WATT    2097152u                // fp32 [1024][1024] W_attnh top, transposed
#define OFF_HPRET   3145728u                // fp32 [1024][512]  Hpre TRANSPOSED
#define OFF_XIOU    3670016u                // fp32 [256][3072]
#define OFF_XF      4456448u                // fp32 [256][1024]
#define OFF_G       4718592u                // bf16 [512][4096]  G = H @ Wg
#define OFF_HT      5767168u                // fp32 [1024][512]  H transposed
#define OFF_HCOL    6291456u                // fp32 [1024]
#define OFF_HCOLW   6292480u                // fp32 [4096]  Hcol @ Wg
#define OFF_SCORED  6297600u                // f64 [2][8][512] count-biased score copies, COPY-MAJOR (zeroed)
#define OFF_HLINE   6313984u                // u64 [128][8]: 8 packets {f32 h, u32 epoch} per block (zeroed)

// R20 recurrent (VERIFIED 1295us): 128 blocks x 8 cols; narrow polls,
// fused flag-in-payload, copy-major single-XCD atomic lines, depth 16.
#define BIAS32  4294967296.0                // 2^32
#define SUBBIAS (16.0 * 4294967296.0)       // 2^36
#define DONE_TH (16.0 * 4294967296.0 - 1073741824.0)   // 16*2^32 - 2^30

typedef __attribute__((ext_vector_type(8))) short short8;
typedef __attribute__((ext_vector_type(4))) float f32x4;

__device__ inline float fast_tanh(float v) {
    float x = fminf(fmaxf(v, -15.f), 15.f);
    float z = __expf(2.f * x);
    return (z - 1.f) / (z + 1.f);
}
__device__ inline float sigm(float v) { return 1.f / (1.f + __expf(-v)); }

__device__ inline float wave_red(float v) {
#pragma unroll
    for (int s = 32; s > 0; s >>= 1) v += __shfl_down(v, s, 64);
    return v;
}

__device__ __host__ inline unsigned short f2b(float f) {
    __hip_bfloat16 h = __float2bfloat16(f);
    return *(unsigned short*)&h;
}
__device__ inline float b2f(unsigned short u) {
    union { unsigned i; float f; } v; v.i = ((unsigned)u) << 16; return v.f;
}

// device-scope relaxed atomics
__device__ inline double gloadd(const double* p) {
    return __hip_atomic_load(p, __ATOMIC_RELAXED, __HIP_MEMORY_SCOPE_AGENT);
}
__device__ inline void gstored(double* p, double v) {
    __hip_atomic_store(p, v, __ATOMIC_RELAXED, __HIP_MEMORY_SCOPE_AGENT);
}
__device__ inline void gatomicd(double* p, double v) {
    __hip_atomic_fetch_add(p, v, __ATOMIC_RELAXED, __HIP_MEMORY_SCOPE_AGENT);
}
__device__ inline unsigned long long gloadu64(const unsigned long long* p) {
    return __hip_atomic_load(p, __ATOMIC_RELAXED, __HIP_MEMORY_SCOPE_AGENT);
}
__device__ inline void gstoreu64(unsigned long long* p, unsigned long long v) {
    __hip_atomic_store(p, v, __ATOMIC_RELAXED, __HIP_MEMORY_SCOPE_AGENT);
}

// -------- precompute kernels --------

__global__ void build_wg(const float* __restrict__ Wiouh, const float* __restrict__ Wfh,
                         unsigned short* __restrict__ Wgb) {
    int k = blockIdx.y;
    int g = blockIdx.x * 256 + threadIdx.x;
    unsigned a = f2b(Wiouh[k * 3072 + g]);
    unsigned b = f2b(Wiouh[k * 3072 + 1024 + g]);
    unsigned c = f2b(Wiouh[k * 3072 + 2048 + g]);
    unsigned d = f2b(Wfh[k * 1024 + g]);
    uint2 p; p.x = a | (b << 16); p.y = c | (d << 16);
    *(uint2*)(Wgb + (size_t)k * 4096 + 4 * g) = p;
}

__global__ void transpose_g(const float* __restrict__ src, float* __restrict__ dst,
                            int R, int C) {
    __shared__ float tile[32][33];
    int c = blockIdx.x * 32 + threadIdx.x;
    int r0 = blockIdx.y * 32;
    for (int i = threadIdx.y; i < 32; i += 8)
        tile[i][threadIdx.x] = src[(size_t)(r0 + i) * C + c];
    __syncthreads();
    int r = r0 + threadIdx.x;
    int c0 = blockIdx.x * 32;
    for (int i = threadIdx.y; i < 32; i += 8)
        dst[(size_t)(c0 + i) * R + r] = tile[threadIdx.x][i];
}

// R21: bf16-MFMA GEMM for all precompute matmuls (was fp32 VALU tile at
// ~15 TF = ~470us total). fp32 inputs converted to bf16 during LDS
// staging; fp32 accumulation via v_mfma_f32_16x16x32_bf16.
// Modes: Gb!=null -> interleaved-bf16 G store (no bias);
//        else C = A@B (+b1)(+b2), optional transposed store.
// Layout notes: A-row and B-col maps are lane&15 (shape-invariant on
// CDNA); any consistent k-slot permutation cancels between A and B
// fragments; C/D map col=lane&15, row=(lane>>4)*4+reg [m89-verified].
__global__ __launch_bounds__(256) void mfma_gemm(
    const float* __restrict__ A, const float* __restrict__ B,
    const float* __restrict__ b1, const float* __restrict__ b2,
    float* __restrict__ C, unsigned short* __restrict__ Gb,
    int M, int N, int K, int tr, int cofs) {
    __shared__ unsigned short As[64 * 40];   // [row][k] bf16, pad 32->40
    __shared__ unsigned short Bs[64 * 40];   // [col][k] bf16 (B transposed)
    const int t = threadIdx.x;
    const int m0 = blockIdx.y * 64, n0 = blockIdx.x * 64;
    const int l = t & 63, w = t >> 6;
    const int fr = l & 15, fk = (l >> 4) * 8;
    const int ar = t >> 2, ak = (t & 3) * 8;   // A stage: row, k8
    const int bn = t >> 2, bk = (t & 3) * 8;   // B stage: col, k8
    f32x4 acc[4] = {};

    for (int kk = 0; kk < K; kk += 32) {
        // load tile (global) before barrier: hides latency under prev MFMA
        const float4 a0 = *(const float4*)(A + (size_t)(m0 + ar) * K + kk + ak);
        const float4 a1 = *(const float4*)(A + (size_t)(m0 + ar) * K + kk + ak + 4);
        short8 av;
        av[0] = f2b(a0.x); av[1] = f2b(a0.y); av[2] = f2b(a0.z); av[3] = f2b(a0.w);
        av[4] = f2b(a1.x); av[5] = f2b(a1.y); av[6] = f2b(a1.z); av[7] = f2b(a1.w);
        short8 bv;
#pragma unroll
        for (int i = 0; i < 8; i++)
            bv[i] = f2b(B[(size_t)(kk + bk + i) * N + n0 + bn]);
        __syncthreads();                       // prev-iter LDS reads done
        *(short8*)(As + ar * 40 + ak) = av;
        *(short8*)(Bs + bn * 40 + bk) = bv;
        __syncthreads();
        const short8 af = *(const short8*)(As + (w * 16 + fr) * 40 + fk);
#pragma unroll
        for (int c = 0; c < 4; c++) {
            const short8 bf = *(const short8*)(Bs + (c * 16 + fr) * 40 + fk);
            acc[c] = __builtin_amdgcn_mfma_f32_16x16x32_bf16(af, bf, acc[c], 0, 0, 0);
        }
    }
#pragma unroll
    for (int c = 0; c < 4; c++) {
#pragma unroll
        for (int r = 0; r < 4; r++) {
            int m = m0 + w * 16 + (l >> 4) * 4 + r;
            int n = n0 + c * 16 + (l & 15);
            float v = acc[c][r];
            if (Gb) {
                int cp = 4 * (n & 1023) + (n >> 10) + cofs;
                Gb[(size_t)m * 4096 + cp] = f2b(v);
            } else {
                if (b1) v += b1[n];
                if (b2) v += b2[n];
                if (tr) C[(size_t)n * M + m] = v;
                else    C[(size_t)m * N + n] = v;
            }
        }
    }
}

__global__ void colsum_k(const float* __restrict__ H, float* __restrict__ out) {
    int k = blockIdx.x * 256 + threadIdx.x;
    float s = 0.f;
#pragma unroll 8
    for (int r = 0; r < MROWS; r++) s += H[(size_t)r * MDIM + k];
    out[k] = s;
}

__global__ void hcolw_k(const float* __restrict__ Hcol,
                        const unsigned short* __restrict__ Wgb,
                        float* __restrict__ HcolW) {
    int j = blockIdx.x * 256 + threadIdx.x;
    float acc = 0.f;
#pragma unroll 8
    for (int k = 0; k < 1024; k++)
        acc = fmaf(Hcol[k], b2f(Wgb[(size_t)k * 4096 + j]), acc);
    HcolW[j] = acc;
}

__device__ inline float sum8(const float* s) {
    return s[0] + s[1] + s[2] + s[3] + s[4] + s[5] + s[6] + s[7];
}

// -------- persistent recurrent kernel (R20, verified 1295us, UNCHANGED) --------
__global__ __launch_bounds__(NTHR, 2) void recurrent(
    const unsigned short* __restrict__ Wgb, const float* __restrict__ WatT,
    const float* __restrict__ HpreT, const float* __restrict__ HT,
    const float* __restrict__ Hcol, const float* __restrict__ HcolW,
    const unsigned short* __restrict__ Gb, const float* __restrict__ X_iou,
    const float* __restrict__ X_f, const float* __restrict__ Wa,
    unsigned long long* hline, double* scored, float* out) {

    const int b = blockIdx.x, t = threadIdx.x;
    const int x = b & 7, y = b >> 3;          // y in [0,16)
    const int g_col = x * 128 + y * 8;        // block's 8 output/attention cols
    const int j0 = x * 512 + y * 32;          // block's 32 interleaved gate cols
    float creg = 0.f;                          // cell state (threads t<8)
    __shared__ float smem[2648];
    float* hs   = smem;          // 1056 padded h (current)
    float* le   = smem + 1056;   // 512 e
    float* red  = smem + 1568;   // [16][32] s1 partials (written in X overlap)
    float* red2 = smem + 2080;   // [16][32] s2 partials
    float* sred = smem + 2592;   // 8  (S partials, 1/wave)
    float* sred2= smem + 2600;   // 8  (P per col, 1/wave)
    float* dotb = smem + 2608;   // 32
    float* attr = smem + 2640;   // 8  (att_v per col, 1/wave)

    const int jt = t & 31, kq = t >> 5;       // gates: 16 k-groups x 32 cols
    const int li = t & 63, tr = t >> 6;       // lane, wave id (0..7)
    const int tl = t & 127, hi = t >> 7;      // h-poll: 4 thr/line, 2 packets

    // ---- hoist step-invariant loads into registers ----
    float wregf[64];
#pragma unroll
    for (int i = 0; i < 64; i++)
        wregf[i] = b2f(Wgb[(size_t)(kq * 64 + i) * 4096 + j0 + jt]);
    float gregf[32];
#pragma unroll
    for (int i = 0; i < 32; i++)
        gregf[i] = b2f(Gb[(size_t)(kq * 32 + i) * 4096 + j0 + jt]);
    float watreg[16];
#pragma unroll
    for (int i = 0; i < 16; i++)
        watreg[i] = WatT[(size_t)(g_col + tr) * 1024 + i * 64 + li];
    float htr[8], hpr[8], wa8[8];
#pragma unroll
    for (int i = 0; i < 8; i++)
        htr[i] = HT[(size_t)(g_col + tr) * 512 + li + 64 * i];
#pragma unroll
    for (int c = 0; c < 8; c++) {
        hpr[c] = HpreT[(size_t)(g_col + c) * 512 + t];
        wa8[c] = Wa[g_col + c];
    }
    const float hcw   = (t < 32) ? HcolW[j0 + t] : 0.f;
    const float hcolg = (t < 8) ? Hcol[g_col + t] : 0.f;

    // ---- prime: s1 partials = 0 for step 0 (hs fully written in X(0)) ----
    red[kq * 32 + jt] = 0.f;

    for (int st = 0; st < T_STEPS; st++) {
        // ---- Y: e (poll 8 strided copies) + gates + h packets + out ----
        float xi0 = 0.f, xi1 = 0.f, xi2 = 0.f, xf0 = 0.f;
        if (t < 8) {                      // issued before poll: latency hidden
            int g = g_col + t;
            xi0 = X_iou[(size_t)st * 3072 + g];
            xi1 = X_iou[(size_t)st * 3072 + 1024 + g];
            xi2 = X_iou[(size_t)st * 3072 + 2048 + g];
            xf0 = X_f[(size_t)st * 1024 + g];
        }
        float sc = 0.f;
        if (st > 0) {
            const double* sp = scored + (size_t)((st + 1) & 1) * 4096 + t;
            double vv[8];
            for (;;) {
                bool ok = true;
#pragma unroll
                for (int c = 0; c < 8; c++) {
                    vv[c] = gloadd(sp + c * 512);
                    ok = ok && (vv[c] > DONE_TH);
                }
                if (ok) break;
                __builtin_amdgcn_s_sleep(1);
            }
            double accd = 0.0;
#pragma unroll
            for (int c = 0; c < 8; c++) accd += (vv[c] - SUBBIAS);
            sc = (float)accd;
        }
        float evv = __expf(sc);
        le[t] = evv;
        float sv = wave_red(evv);
        if ((t & 63) == 0) sred[t >> 6] = sv;
        __syncthreads();                       // #1
        // s2 (G-correction) from registers: rows kq*32+i
        float a2 = 0.f;
#pragma unroll
        for (int i = 0; i < 32; i++)
            a2 = fmaf(le[kq * 32 + i], gregf[i], a2);
        red2[kq * 32 + jt] = a2;
        // P for block's 8 out-cols: wave tr owns col g_col+tr
        float pp = 0.f;
#pragma unroll
        for (int i = 0; i < 8; i++)
            pp = fmaf(le[li + 64 * i], htr[i], pp);
        pp = wave_red(pp);
        if ((t & 63) == 0) sred2[t >> 6] = pp;
        __syncthreads();                       // #2
        if (t < 32) {                          // wave-0 writes dotb...
            float s1 = 0.f, s2 = 0.f;
#pragma unroll
            for (int q = 0; q < 16; q++) { s1 += red[q * 32 + t]; s2 += red2[q * 32 + t]; }
            float S = sum8(sred);
            float invS = (st == 0) ? 0.f : 1.f / S;
            float hw = (st == 0) ? 0.f : hcw;
            dotb[t] = s1 + hw - invS * s2;
        }
        if (t < 8) {                           // ...read also wave-0: in-order LDS
            int g = g_col + t;
            if (st > 0) {
                float S = sum8(sred);
                float P = sred2[t];
                out[(size_t)(st - 1) * 1024 + g] =
                    hcolg + hs[g + (g >> 5)] - P / S;
            }
            float di = dotb[t * 4 + 0] + xi0;
            float doo = dotb[t * 4 + 1] + xi1;
            float du = dotb[t * 4 + 2] + xi2;
            float df = dotb[t * 4 + 3] + xf0;
            float ig = sigm(di), og = sigm(doo), fg = sigm(df);
            float ug = fast_tanh(du);
            creg = ig * ug + fg * creg;
            float hv = og * fast_tanh(creg);
            // fused payload+flag: one 8B single-copy-atomic packet
            unsigned long long pkt =
                ((unsigned long long)(unsigned)(st + 1) << 32) | __float_as_uint(hv);
            gstoreu64(hline + (size_t)b * 8 + t, pkt);
        }
        __syncthreads();                       // #4: hs rewritten in X below

        // ---- X: poll-with-payload h -> LDS, att_v, biased f64 adds ----
        {
            const unsigned long long* lp = hline + (size_t)tl * 8 + hi * 2;
            const unsigned tgt = (unsigned)(st + 1);
            unsigned long long u0, u1;
            for (;;) {
                u0 = gloadu64(lp);
                u1 = gloadu64(lp + 1);
                if ((unsigned)(u0 >> 32) >= tgt && (unsigned)(u1 >> 32) >= tgt) break;
                __builtin_amdgcn_s_sleep(1);
            }
            int gc = (tl & 7) * 128 + (tl >> 3) * 8 + hi * 2;
            union { unsigned u; float f; } c0, c1;
            c0.u = (unsigned)u0; c1.u = (unsigned)u1;
            hs[gc + (gc >> 5)] = c0.f;
            int g1 = gc + 1; hs[g1 + (g1 >> 5)] = c1.f;
        }
        __syncthreads();                       // #5: hs ready AND all 128 lines
                                               // verified >= st+1 block-wide
        // zero the buffer all Y(st) consumed: safe after #5 (every block has
        // passed its Y(st) reads, proven by the 128 epochs). 32 doubles per
        // block cover the 4096-double buffer exactly once.
        if (t < 32)
            gstored(scored + (size_t)((st + 1) & 1) * 4096 + (size_t)b * 32 + t, 0.0);
        {
            // att_v: wave tr computes col g_col+tr (16 fma/lane from hs)
            float acc = 0.f;
#pragma unroll
            for (int i = 0; i < 16; i++) {
                int k = i * 64 + li;
                acc = fmaf(watreg[i], hs[k + (k >> 5)], acc);
            }
            acc = wave_red(acc);
            if ((t & 63) == 0) attr[t >> 6] = acc;
            __syncthreads();                   // #6 (implicit vmcnt(0): zeroes)
            float ps = 0.f;
#pragma unroll
            for (int c = 0; c < 8; c++)
                ps = fmaf(wa8[c], fast_tanh(hpr[c] + attr[c]), ps);
            __asm__ volatile("" ::: "memory");
            __builtin_amdgcn_s_waitcnt(0);     // own zero-store drained first
            gatomicd(scored + (size_t)(st & 1) * 4096 + x * 512 + t,
                     (double)ps + BIAS32);
        }
        // s1 overlap for next step's gates (runs under the exchange latency)
        {
            float a = 0.f;
#pragma unroll
            for (int i = 0; i < 64; i++) {
                int k = kq * 64 + i;
                a = fmaf(hs[k + (k >> 5)], wregf[i], a);
            }
            red[kq * 32 + jt] = a;
        }
    }

    // ---- Epilogue: out[T-1] (Y(T) without gates) ----
    {
        const double* sp = scored + (size_t)((T_STEPS + 1) & 1) * 4096 + t;
        double vv[8];
        for (;;) {
            bool ok = true;
#pragma unroll
            for (int c = 0; c < 8; c++) {
                vv[c] = gloadd(sp + c * 512);
                ok = ok && (vv[c] > DONE_TH);
            }
            if (ok) break;
            __builtin_amdgcn_s_sleep(1);
        }
        double accd = 0.0;
#pragma unroll
        for (int c = 0; c < 8; c++) accd += (vv[c] - SUBBIAS);
        float evv = __expf((float)accd);
        le[t] = evv;
        float sv = wave_red(evv);
        if ((t & 63) == 0) sred[t >> 6] = sv;
        __syncthreads();
        float pp = 0.f;
#pragma unroll
        for (int i = 0; i < 8; i++)
            pp = fmaf(le[li + 64 * i], htr[i], pp);
        pp = wave_red(pp);
        if ((t & 63) == 0) sred2[t >> 6] = pp;
        __syncthreads();
        if (t < 8) {
            int g = g_col + t;
            float S = sum8(sred);
            float P = sred2[t];
            out[(size_t)(T_STEPS - 1) * 1024 + g] =
                hcolg + hs[g + (g >> 5)] - P / S;   // hs = h(T-1) from X(T-1)
        }
    }
}

extern "C" void kernel_launch(void* const* d_in, const int* in_sizes, int n_in,
                              void* d_out, int out_size, void* d_ws, size_t ws_size,
                              hipStream_t stream) {
    const float* inputs  = (const float*)d_in[0];
    const float* hiddn   = (const float*)d_in[1];
    const float* W_ioux  = (const float*)d_in[2];
    const float* b_ioux  = (const float*)d_in[3];
    const float* W_iouh  = (const float*)d_in[4];
    const float* b_iouh  = (const float*)d_in[5];
    const float* W_fx    = (const float*)d_in[6];
    const float* b_fx    = (const float*)d_in[7];
    const float* W_fh    = (const float*)d_in[8];
    const float* b_fh    = (const float*)d_in[9];
    const float* Wa      = (const float*)d_in[10];
    const float* W_attnh = (const float*)d_in[11];
    const float* b_attnh = (const float*)d_in[12];

    float* ws = (float*)d_ws;
    unsigned short* Wgb = (unsigned short*)(ws + OFF_WGB);
    float* WatT  = ws + OFF_WATT;
    float* HpreT = ws + OFF_HPRET;
    float* X_iou = ws + OFF_XIOU;
    float* X_f   = ws + OFF_XF;
    unsigned short* Gb = (unsigned short*)(ws + OFF_G);
    float* HT    = ws + OFF_HT;
    float* Hcol  = ws + OFF_HCOL;
    float* HcolW = ws + OFF_HCOLW;
    double* scored = (double*)(ws + OFF_SCORED);
    unsigned long long* hline = (unsigned long long*)(ws + OFF_HLINE);
    float* out   = (float*)d_out;

    // zero score copies (2x4096 f64 = 16384 floats) + hline (128x8 u64 = 2048 floats)
    hipMemsetAsync(ws + OFF_SCORED, 0, (16384 + 2048) * sizeof(float), stream);

    build_wg<<<dim3(4, 1024), 256, 0, stream>>>(W_iouh, W_fh, Wgb);
    transpose_g<<<dim3(32, 32), dim3(32, 8), 0, stream>>>(W_attnh, WatT, 1024, 1024);
    transpose_g<<<dim3(32, 16), dim3(32, 8), 0, stream>>>(hiddn, HT, 512, 1024);
    // MFMA precompute GEMMs (R21)
    mfma_gemm<<<dim3(48, 4), 256, 0, stream>>>(inputs, W_ioux, b_ioux, b_iouh, X_iou, nullptr, 256, 3072, 1024, 0, 0);
    mfma_gemm<<<dim3(16, 4), 256, 0, stream>>>(inputs, W_fx, b_fx, b_fh, X_f, nullptr, 256, 1024, 1024, 0, 0);
    mfma_gemm<<<dim3(16, 8), 256, 0, stream>>>(hiddn, W_attnh + 1024 * 1024, b_attnh, nullptr, HpreT, nullptr, 512, 1024, 1024, 1, 0);
    colsum_k<<<4, 256, 0, stream>>>(hiddn, Hcol);
    hcolw_k<<<16, 256, 0, stream>>>(Hcol, Wgb, HcolW);
    mfma_gemm<<<dim3(48, 8), 256, 0, stream>>>(hiddn, W_iouh, nullptr, nullptr, nullptr, Gb, 512, 3072, 1024, 0, 0);
    mfma_gemm<<<dim3(16, 8), 256, 0, stream>>>(hiddn, W_fh, nullptr, nullptr, nullptr, Gb, 512, 1024, 1024, 0, 3);

    recurrent<<<GRID, NTHR, 0, stream>>>(Wgb, WatT, HpreT, HT, Hcol, HcolW, Gb,
                                         X_iou, X_f, Wa, hline, scored, out);
}